// Round 4
// baseline (132.990 us; speedup 1.0000x reference)
//
#include <hip/hip_runtime.h>

// SNN loss, MI355X. Round 4: counted-vmcnt two-barrier K-loop (T4).
//  k_stats/k_stats2: global std (ddof=1) in double precision
//  k_norm:           xs = x*inv_std -> bf16 (ws), row sqn (fp32)
//  k_main:           upper-triangular 128x128 MFMA tiles of xs·xs^T (2080
//                    blocks); LDS double-buffered, counted s_waitcnt vmcnt(N)
//                    (never 0 mid-loop) + raw s_barrier pair per K-step, so
//                    next-tile loads stay in flight across barriers. Epilogue
//                    reduction arrays overlay the staging LDS (32 KB total).
//  k_rows/k_final:   combine partials per row, mean, negate

#define NROW 8192
#define NDIM 512
#define BM   128
#define BN   128
#define BK   32
#define NK   (NDIM / BK)           // 16 K-steps
#define NT   (NROW / BN)           // 64 tiles per dim
#define NBLK (NT * (NT + 1) / 2)   // 2080 upper-tri blocks

typedef __attribute__((ext_vector_type(8))) short bf16x8;
typedef __attribute__((ext_vector_type(4))) float f32x4;

#define NEG_INF (-__builtin_inff())

// ---- workspace layout (bytes) ----
static const size_t WS_PART = 0;                                   // 256*2 doubles = 4096
static const size_t WS_SCAL = 4096;                                // inv_std float
static const size_t WS_XB   = 8192;                                // bf16 xs: 8192*512*2 = 8388608
static const size_t WS_SQN  = WS_XB + (size_t)NROW * NDIM * 2;     // 8192 floats
static const size_t WS_P4   = WS_SQN + (size_t)NROW * 4;           // 64*8192 float4 = 8388608
static const size_t WS_ROWV = WS_P4 + (size_t)NT * NROW * 16;      // 8192 floats

__device__ __forceinline__ unsigned short f2bf(float f) {
    unsigned int u = __float_as_uint(f);      // finite inputs only
    u += 0x7FFFu + ((u >> 16) & 1u);          // round-to-nearest-even
    return (unsigned short)(u >> 16);
}

#define GLD_LDS16(gp, lp) __builtin_amdgcn_global_load_lds( \
    (const __attribute__((address_space(1))) unsigned int*)(gp), \
    (__attribute__((address_space(3))) unsigned int*)(lp), 16, 0, 0)

// ---------------- stats: sum / sumsq ----------------
__global__ __launch_bounds__(256) void k_stats(const float* __restrict__ x,
                                               double* __restrict__ part) {
    int t = blockIdx.x * 256 + threadIdx.x;
    const float4* x4 = (const float4*)x;
    double s = 0.0, ss = 0.0;
    for (int i = t; i < (NROW * NDIM / 4); i += 256 * 256) {
        float4 v = x4[i];
        double a = v.x, b = v.y, c = v.z, d = v.w;
        s  += (a + b) + (c + d);
        ss += (a * a + b * b) + (c * c + d * d);
    }
#pragma unroll
    for (int off = 32; off >= 1; off >>= 1) {
        s  += __shfl_xor(s, off, 64);
        ss += __shfl_xor(ss, off, 64);
    }
    __shared__ double sa[4], sb[4];
    int w = threadIdx.x >> 6, lane = threadIdx.x & 63;
    if (lane == 0) { sa[w] = s; sb[w] = ss; }
    __syncthreads();
    if (threadIdx.x == 0) {
        part[blockIdx.x * 2]     = sa[0] + sa[1] + sa[2] + sa[3];
        part[blockIdx.x * 2 + 1] = sb[0] + sb[1] + sb[2] + sb[3];
    }
}

__global__ __launch_bounds__(256) void k_stats2(const double* __restrict__ part,
                                                float* __restrict__ scal) {
    int t = threadIdx.x;
    double s = part[t * 2], ss = part[t * 2 + 1];
#pragma unroll
    for (int off = 32; off >= 1; off >>= 1) {
        s  += __shfl_xor(s, off, 64);
        ss += __shfl_xor(ss, off, 64);
    }
    __shared__ double sa[4], sb[4];
    int w = t >> 6, lane = t & 63;
    if (lane == 0) { sa[w] = s; sb[w] = ss; }
    __syncthreads();
    if (t == 0) {
        double S = sa[0] + sa[1] + sa[2] + sa[3];
        double SS = sb[0] + sb[1] + sb[2] + sb[3];
        const double N = (double)NROW * (double)NDIM;
        double var = (SS - S * S / N) / (N - 1.0);   // ddof=1
        scal[0] = (float)(1.0 / sqrt(var));
    }
}

// ---------------- normalize -> bf16 + row sqn ----------------
__global__ __launch_bounds__(256) void k_norm(const float* __restrict__ x,
                                              const float* __restrict__ scal,
                                              unsigned short* __restrict__ xb,
                                              float* __restrict__ sqn) {
    int w = threadIdx.x >> 6, lane = threadIdx.x & 63;
    int row = blockIdx.x * 4 + w;
    float is = scal[0];
    const float4* xr = (const float4*)(x + (size_t)row * NDIM);
    ushort4* xo = (ushort4*)(xb + (size_t)row * NDIM);
    float ss = 0.f;
#pragma unroll
    for (int ph = 0; ph < 2; ++ph) {
        float4 v = xr[ph * 64 + lane];
        v.x *= is; v.y *= is; v.z *= is; v.w *= is;
        ss += v.x * v.x + v.y * v.y + v.z * v.z + v.w * v.w;
        xo[ph * 64 + lane] = make_ushort4(f2bf(v.x), f2bf(v.y), f2bf(v.z), f2bf(v.w));
    }
#pragma unroll
    for (int off = 32; off >= 1; off >>= 1) ss += __shfl_xor(ss, off, 64);
    if (lane == 0) sqn[row] = ss;
}

// ---------------- main: upper-tri GEMM tile + dual-sided fused LSE ----------------
__global__ __launch_bounds__(256, 4) void k_main(const unsigned short* __restrict__ xb,
                                                 const float* __restrict__ sqn,
                                                 const int* __restrict__ y,
                                                 const float* __restrict__ Tp,
                                                 float4* __restrict__ part) {
    // 32 KB: [buf][A|B][128*32 bf16]. Epilogue red arrays overlay buf 0.
    __shared__ __attribute__((aligned(16))) unsigned short smem[2][2][BM * BK];
    float* redR = (float*)&smem[0][0][0];      // [128][2][4] floats = 4 KB
    float* redC = (float*)&smem[0][0][2048];   // next 4 KB

    // XCD-bijective swizzle (2080 = 8*260), then upper-tri decode
    int bid = blockIdx.x;
    int bswz = (bid & 7) * (NBLK / 8) + (bid >> 3);
    int L = bswz, rt = 0, rem = NT;
    while (L >= rem) { L -= rem; --rem; ++rt; }
    int ct = rt + L;
    const bool diag = (rt == ct);

    const int tid = threadIdx.x;
    const int w = tid >> 6, lane = tid & 63;
    const int wr = w >> 1, wc = w & 1;           // 2x2 waves, 64x64 each
    const int g = lane >> 4, qq = lane & 15;
    const int rowTile = rt * BM, colTile = ct * BN;

    // per-thread staging coords: chunk q covers tile rows [q*16,q*16+16)
    const int q0 = w * 2, q1 = w * 2 + 1;
    const int e0 = q0 * 512 + lane * 8, e1 = q1 * 512 + lane * 8;
    const int rr0 = e0 >> 5, cc0 = e0 & 31;
    const int rr1 = e1 >> 5, cc1 = e1 & 31;
    const unsigned short* ga0 = xb + (size_t)(rowTile + rr0) * NDIM + cc0;
    const unsigned short* ga1 = xb + (size_t)(rowTile + rr1) * NDIM + cc1;
    const unsigned short* gb0 = xb + (size_t)(colTile + rr0) * NDIM + cc0;
    const unsigned short* gb1 = xb + (size_t)(colTile + rr1) * NDIM + cc1;

    // hoist epilogue operands above the K-loop (latency hides under GEMM)
    float scol[4]; int ycol[4];
#pragma unroll
    for (int ni = 0; ni < 4; ++ni) {
        int C = colTile + wc * 64 + ni * 16 + qq;
        scol[ni] = sqn[C];
        ycol[ni] = y[C];
    }
    float srow[4][4]; int yrow[4][4];
#pragma unroll
    for (int mi = 0; mi < 4; ++mi)
#pragma unroll
        for (int r = 0; r < 4; ++r) {
            int R = rowTile + wr * 64 + mi * 16 + g * 4 + r;
            srow[mi][r] = sqn[R];
            yrow[mi][r] = y[R];
        }
    const float c2 = __builtin_amdgcn_exp2f(Tp[0] * 3.321928094887362f) * 1.4426950408889634f;

    f32x4 acc[4][4];
    const f32x4 zero = {0.f, 0.f, 0.f, 0.f};
#pragma unroll
    for (int i = 0; i < 4; ++i)
#pragma unroll
        for (int j = 0; j < 4; ++j) acc[i][j] = zero;

    // prologue: stage K-step 0 into buffer 0
    GLD_LDS16(ga0, &smem[0][0][q0 * 512]);
    GLD_LDS16(ga1, &smem[0][0][q1 * 512]);
    if (!diag) {
        GLD_LDS16(gb0, &smem[0][1][q0 * 512]);
        GLD_LDS16(gb1, &smem[0][1][q1 * 512]);
    }

    int cur = 0;
    for (int kt = 0; kt < NK; ++kt) {
        // issue next K-step's loads; they stay in flight across both barriers
        if (kt + 1 < NK) {
            const int k1 = (kt + 1) * BK;
            GLD_LDS16(ga0 + k1, &smem[cur ^ 1][0][q0 * 512]);
            GLD_LDS16(ga1 + k1, &smem[cur ^ 1][0][q1 * 512]);
            if (!diag) {
                GLD_LDS16(gb0 + k1, &smem[cur ^ 1][1][q0 * 512]);
                GLD_LDS16(gb1 + k1, &smem[cur ^ 1][1][q1 * 512]);
                asm volatile("s_waitcnt vmcnt(4)" ::: "memory");  // cur's 4 loads done
            } else {
                asm volatile("s_waitcnt vmcnt(2)" ::: "memory");  // cur's 2 loads done
            }
        } else {
            asm volatile("s_waitcnt vmcnt(0)" ::: "memory");
        }
        __builtin_amdgcn_s_barrier();            // all waves: cur buffer ready

        const unsigned short* AA = &smem[cur][0][0];
        const unsigned short* BB = diag ? AA : &smem[cur][1][0];
        bf16x8 af[4], bfr[4];
#pragma unroll
        for (int mi = 0; mi < 4; ++mi)
            af[mi] = *(const bf16x8*)&AA[(wr * 64 + mi * 16 + qq) * BK + g * 8];
#pragma unroll
        for (int ni = 0; ni < 4; ++ni)
            bfr[ni] = *(const bf16x8*)&BB[(wc * 64 + ni * 16 + qq) * BK + g * 8];
#pragma unroll
        for (int mi = 0; mi < 4; ++mi)
#pragma unroll
            for (int ni = 0; ni < 4; ++ni)
                acc[mi][ni] = __builtin_amdgcn_mfma_f32_16x16x32_bf16(af[mi], bfr[ni],
                                                                      acc[mi][ni], 0, 0, 0);
        asm volatile("s_waitcnt lgkmcnt(0)" ::: "memory");  // reads drained to regs
        __builtin_amdgcn_s_barrier();            // release cur for overwrite
        cur ^= 1;
    }

    // ---- epilogue ----
    // phase 1: acc := s2 in place; label-match bits -> mm0/mm1
    unsigned mm0 = 0, mm1 = 0;
#pragma unroll
    for (int mi = 0; mi < 4; ++mi) {
#pragma unroll
        for (int r = 0; r < 4; ++r) {
            const int R = rowTile + wr * 64 + mi * 16 + g * 4 + r;
#pragma unroll
            for (int ni = 0; ni < 4; ++ni) {
                const int C = colTile + wc * 64 + ni * 16 + qq;
                float sq = fmaf(-2.f, acc[mi][ni][r], srow[mi][r] + scol[ni]);
                sq = fmaxf(sq, 0.f);
                float s2 = -__builtin_amdgcn_sqrtf(sq) * c2;
                if (R == C) s2 = NEG_INF;          // diagonal mask
                acc[mi][ni][r] = s2;
                unsigned bit = (yrow[mi][r] == ycol[ni]) ? 1u : 0u;
                int idx = ((mi & 1) * 4 + r) * 4 + ni;
                if (mi < 2) mm0 |= bit << idx; else mm1 |= bit << idx;
            }
        }
    }

    // phase 2: row-side partials (reduce over ni in-reg + 16 qq lanes)
#pragma unroll
    for (int mi = 0; mi < 4; ++mi) {
        unsigned mmw = (mi < 2) ? mm0 : mm1;
#pragma unroll
        for (int r = 0; r < 4; ++r) {
            float mx = acc[mi][0][r];
#pragma unroll
            for (int ni = 1; ni < 4; ++ni) mx = fmaxf(mx, acc[mi][ni][r]);
#pragma unroll
            for (int off = 1; off <= 8; off <<= 1) mx = fmaxf(mx, __shfl_xor(mx, off, 64));
            float ld = 0.f, ln = 0.f;
#pragma unroll
            for (int ni = 0; ni < 4; ++ni) {
                float e = __builtin_amdgcn_exp2f(acc[mi][ni][r] - mx);  // diag: exp2(-inf)=0
                ld += e;
                ln += ((mmw >> (((mi & 1) * 4 + r) * 4 + ni)) & 1) ? e : 0.f;
            }
#pragma unroll
            for (int off = 1; off <= 8; off <<= 1) {
                ld += __shfl_xor(ld, off, 64);
                ln += __shfl_xor(ln, off, 64);
            }
            if (qq == 0) {
                int lr = wr * 64 + mi * 16 + g * 4 + r;
                redR[(lr * 2 + wc) * 4 + 0] = mx;
                redR[(lr * 2 + wc) * 4 + 1] = ld;
                redR[(lr * 2 + wc) * 4 + 2] = ln;
            }
        }
    }

    // phase 3: col-side partials (reduce over mi,r in-reg + g lanes), off-diag only
    if (!diag) {
#pragma unroll
        for (int ni = 0; ni < 4; ++ni) {
            float mx = NEG_INF;
#pragma unroll
            for (int mi = 0; mi < 4; ++mi)
#pragma unroll
                for (int r = 0; r < 4; ++r) mx = fmaxf(mx, acc[mi][ni][r]);
            mx = fmaxf(mx, __shfl_xor(mx, 16, 64));
            mx = fmaxf(mx, __shfl_xor(mx, 32, 64));
            float ld = 0.f, ln = 0.f;
#pragma unroll
            for (int mi = 0; mi < 4; ++mi) {
                unsigned mmw = (mi < 2) ? mm0 : mm1;
#pragma unroll
                for (int r = 0; r < 4; ++r) {
                    float e = __builtin_amdgcn_exp2f(acc[mi][ni][r] - mx);
                    ld += e;
                    ln += ((mmw >> (((mi & 1) * 4 + r) * 4 + ni)) & 1) ? e : 0.f;
                }
            }
            ld += __shfl_xor(ld, 16, 64); ld += __shfl_xor(ld, 32, 64);
            ln += __shfl_xor(ln, 16, 64); ln += __shfl_xor(ln, 32, 64);
            if (g == 0) {
                int lc = wc * 64 + ni * 16 + qq;
                redC[(lc * 2 + wr) * 4 + 0] = mx;
                redC[(lc * 2 + wr) * 4 + 1] = ld;
                redC[(lc * 2 + wr) * 4 + 2] = ln;
            }
        }
    }
    __syncthreads();

    if (tid < BM) {
        {
            float m0 = redR[(tid * 2 + 0) * 4 + 0], l0 = redR[(tid * 2 + 0) * 4 + 1],
                  n0 = redR[(tid * 2 + 0) * 4 + 2];
            float m1 = redR[(tid * 2 + 1) * 4 + 0], l1 = redR[(tid * 2 + 1) * 4 + 1],
                  n1 = redR[(tid * 2 + 1) * 4 + 2];
            float M = fmaxf(m0, m1);
            float e0 = __builtin_amdgcn_exp2f(m0 - M), e1 = __builtin_amdgcn_exp2f(m1 - M);
            float4 o; o.x = M; o.y = l0 * e0 + l1 * e1; o.z = n0 * e0 + n1 * e1; o.w = 0.f;
            part[(size_t)ct * NROW + rowTile + tid] = o;
        }
        if (!diag) {
            float m0 = redC[(tid * 2 + 0) * 4 + 0], l0 = redC[(tid * 2 + 0) * 4 + 1],
                  n0 = redC[(tid * 2 + 0) * 4 + 2];
            float m1 = redC[(tid * 2 + 1) * 4 + 0], l1 = redC[(tid * 2 + 1) * 4 + 1],
                  n1 = redC[(tid * 2 + 1) * 4 + 2];
            float M = fmaxf(m0, m1);
            float e0 = __builtin_amdgcn_exp2f(m0 - M), e1 = __builtin_amdgcn_exp2f(m1 - M);
            float4 o; o.x = M; o.y = l0 * e0 + l1 * e1; o.z = n0 * e0 + n1 * e1; o.w = 0.f;
            part[(size_t)rt * NROW + colTile + tid] = o;
        }
    }
}

// ---------------- combine chunks per row ----------------
__global__ __launch_bounds__(256) void k_rows(const float4* __restrict__ part,
                                              float* __restrict__ rowv) {
    int r = blockIdx.x * 256 + threadIdx.x;
    float M = NEG_INF, L = 0.f, Ln = 0.f;
    for (int ctt = 0; ctt < NT; ++ctt) {
        float4 p = part[(size_t)ctt * NROW + r];
        float m = p.x;                             // always finite
        if (m > M) {
            float sc = __builtin_amdgcn_exp2f(M - m);  // first iter: exp2(-inf)=0
            L *= sc; Ln *= sc; M = m;
        }
        float s2 = __builtin_amdgcn_exp2f(m - M);
        L  += p.y * s2;
        Ln += p.z * s2;
    }
    float v = (Ln > 0.f) ? (__builtin_amdgcn_logf(Ln) - __builtin_amdgcn_logf(L))
                               * 0.69314718055994530942f
                         : 0.f;
    rowv[r] = v;
}

__global__ __launch_bounds__(256) void k_final(const float* __restrict__ rowv,
                                               float* __restrict__ out) {
    float s = 0.f;
    for (int i = threadIdx.x; i < NROW; i += 256) s += rowv[i];
#pragma unroll
    for (int off = 32; off >= 1; off >>= 1) s += __shfl_xor(s, off, 64);
    __shared__ float sa[4];
    int w = threadIdx.x >> 6, lane = threadIdx.x & 63;
    if (lane == 0) sa[w] = s;
    __syncthreads();
    if (threadIdx.x == 0) out[0] = -((sa[0] + sa[1] + sa[2] + sa[3]) / (float)NROW);
}

extern "C" void kernel_launch(void* const* d_in, const int* in_sizes, int n_in,
                              void* d_out, int out_size, void* d_ws, size_t ws_size,
                              hipStream_t stream) {
    (void)in_sizes; (void)n_in; (void)out_size; (void)ws_size;
    const float* x  = (const float*)d_in[0];
    const int*   y  = (const int*)d_in[1];
    const float* Tp = (const float*)d_in[2];
    float* out = (float*)d_out;

    char* ws = (char*)d_ws;
    double*         part2 = (double*)(ws + WS_PART);
    float*          scal  = (float*)(ws + WS_SCAL);
    unsigned short* xb    = (unsigned short*)(ws + WS_XB);
    float*          sqn   = (float*)(ws + WS_SQN);
    float4*         p4    = (float4*)(ws + WS_P4);
    float*          rowv  = (float*)(ws + WS_ROWV);

    k_stats <<<256, 256, 0, stream>>>(x, part2);
    k_stats2<<<1,   256, 0, stream>>>(part2, scal);
    k_norm  <<<NROW / 4, 256, 0, stream>>>(x, scal, xb, sqn);
    k_main  <<<NBLK, 256, 0, stream>>>(xb, sqn, y, Tp, p4);
    k_rows  <<<NROW / 256, 256, 0, stream>>>(p4, rowv);
    k_final <<<1, 256, 0, stream>>>(rowv, out);
}

// Round 5
// 110.896 us; speedup vs baseline: 1.1992x; 1.1992x over previous
//
#include <hip/hip_runtime.h>

// SNN loss, MI355X. Round 5: counted-vmcnt two-barrier K-loop (T4), spill-free.
//  (R4's regression was scratch spill from launch_bounds(256,4)+operand hoist:
//   WRITE_SIZE 8->116 MB. This round keeps T4, reverts the pressure sources.)
//  k_stats/k_stats2: global std (ddof=1) in double precision
//  k_norm:           xs = x*inv_std -> bf16 (ws), row sqn (fp32)
//  k_main:           upper-triangular 128x128 MFMA tiles of xs·xs^T (2080
//                    blocks); LDS double-buffered, counted s_waitcnt vmcnt(N)
//                    (never 0 mid-loop) + raw s_barrier pair per K-step.
//                    Epilogue reduction arrays overlay the staging LDS.
//  k_rows/k_final:   combine partials per row, mean, negate

#define NROW 8192
#define NDIM 512
#define BM   128
#define BN   128
#define BK   32
#define NK   (NDIM / BK)           // 16 K-steps
#define NT   (NROW / BN)           // 64 tiles per dim
#define NBLK (NT * (NT + 1) / 2)   // 2080 upper-tri blocks

typedef __attribute__((ext_vector_type(8))) short bf16x8;
typedef __attribute__((ext_vector_type(4))) float f32x4;

#define NEG_INF (-__builtin_inff())

// ---- workspace layout (bytes) ----
static const size_t WS_PART = 0;                                   // 256*2 doubles = 4096
static const size_t WS_SCAL = 4096;                                // inv_std float
static const size_t WS_XB   = 8192;                                // bf16 xs: 8192*512*2 = 8388608
static const size_t WS_SQN  = WS_XB + (size_t)NROW * NDIM * 2;     // 8192 floats
static const size_t WS_P4   = WS_SQN + (size_t)NROW * 4;           // 64*8192 float4 = 8388608
static const size_t WS_ROWV = WS_P4 + (size_t)NT * NROW * 16;      // 8192 floats

__device__ __forceinline__ unsigned short f2bf(float f) {
    unsigned int u = __float_as_uint(f);      // finite inputs only
    u += 0x7FFFu + ((u >> 16) & 1u);          // round-to-nearest-even
    return (unsigned short)(u >> 16);
}

#define GLD_LDS16(gp, lp) __builtin_amdgcn_global_load_lds( \
    (const __attribute__((address_space(1))) unsigned int*)(gp), \
    (__attribute__((address_space(3))) unsigned int*)(lp), 16, 0, 0)

// ---------------- stats: sum / sumsq ----------------
__global__ __launch_bounds__(256) void k_stats(const float* __restrict__ x,
                                               double* __restrict__ part) {
    int t = blockIdx.x * 256 + threadIdx.x;
    const float4* x4 = (const float4*)x;
    double s = 0.0, ss = 0.0;
    for (int i = t; i < (NROW * NDIM / 4); i += 256 * 256) {
        float4 v = x4[i];
        double a = v.x, b = v.y, c = v.z, d = v.w;
        s  += (a + b) + (c + d);
        ss += (a * a + b * b) + (c * c + d * d);
    }
#pragma unroll
    for (int off = 32; off >= 1; off >>= 1) {
        s  += __shfl_xor(s, off, 64);
        ss += __shfl_xor(ss, off, 64);
    }
    __shared__ double sa[4], sb[4];
    int w = threadIdx.x >> 6, lane = threadIdx.x & 63;
    if (lane == 0) { sa[w] = s; sb[w] = ss; }
    __syncthreads();
    if (threadIdx.x == 0) {
        part[blockIdx.x * 2]     = sa[0] + sa[1] + sa[2] + sa[3];
        part[blockIdx.x * 2 + 1] = sb[0] + sb[1] + sb[2] + sb[3];
    }
}

__global__ __launch_bounds__(256) void k_stats2(const double* __restrict__ part,
                                                float* __restrict__ scal) {
    int t = threadIdx.x;
    double s = part[t * 2], ss = part[t * 2 + 1];
#pragma unroll
    for (int off = 32; off >= 1; off >>= 1) {
        s  += __shfl_xor(s, off, 64);
        ss += __shfl_xor(ss, off, 64);
    }
    __shared__ double sa[4], sb[4];
    int w = t >> 6, lane = t & 63;
    if (lane == 0) { sa[w] = s; sb[w] = ss; }
    __syncthreads();
    if (t == 0) {
        double S = sa[0] + sa[1] + sa[2] + sa[3];
        double SS = sb[0] + sb[1] + sb[2] + sb[3];
        const double N = (double)NROW * (double)NDIM;
        double var = (SS - S * S / N) / (N - 1.0);   // ddof=1
        scal[0] = (float)(1.0 / sqrt(var));
    }
}

// ---------------- normalize -> bf16 + row sqn ----------------
__global__ __launch_bounds__(256) void k_norm(const float* __restrict__ x,
                                              const float* __restrict__ scal,
                                              unsigned short* __restrict__ xb,
                                              float* __restrict__ sqn) {
    int w = threadIdx.x >> 6, lane = threadIdx.x & 63;
    int row = blockIdx.x * 4 + w;
    float is = scal[0];
    const float4* xr = (const float4*)(x + (size_t)row * NDIM);
    ushort4* xo = (ushort4*)(xb + (size_t)row * NDIM);
    float ss = 0.f;
#pragma unroll
    for (int ph = 0; ph < 2; ++ph) {
        float4 v = xr[ph * 64 + lane];
        v.x *= is; v.y *= is; v.z *= is; v.w *= is;
        ss += v.x * v.x + v.y * v.y + v.z * v.z + v.w * v.w;
        xo[ph * 64 + lane] = make_ushort4(f2bf(v.x), f2bf(v.y), f2bf(v.z), f2bf(v.w));
    }
#pragma unroll
    for (int off = 32; off >= 1; off >>= 1) ss += __shfl_xor(ss, off, 64);
    if (lane == 0) sqn[row] = ss;
}

// ---------------- main: upper-tri GEMM tile + dual-sided fused LSE ----------------
__global__ __launch_bounds__(256, 3) void k_main(const unsigned short* __restrict__ xb,
                                                 const float* __restrict__ sqn,
                                                 const int* __restrict__ y,
                                                 const float* __restrict__ Tp,
                                                 float4* __restrict__ part) {
    // 32 KB: [buf][A|B][128*32 bf16]. Epilogue red arrays overlay buf 0.
    __shared__ __attribute__((aligned(16))) unsigned short smem[2][2][BM * BK];
    float* redR = (float*)&smem[0][0][0];      // [128][2][4] floats = 4 KB
    float* redC = (float*)&smem[0][0][2048];   // next 4 KB

    // XCD-bijective swizzle (2080 = 8*260), then upper-tri decode
    int bid = blockIdx.x;
    int bswz = (bid & 7) * (NBLK / 8) + (bid >> 3);
    int L = bswz, rt = 0, rem = NT;
    while (L >= rem) { L -= rem; --rem; ++rt; }
    int ct = rt + L;
    const bool diag = (rt == ct);

    const int tid = threadIdx.x;
    const int w = tid >> 6, lane = tid & 63;
    const int wr = w >> 1, wc = w & 1;           // 2x2 waves, 64x64 each
    const int g = lane >> 4, qq = lane & 15;
    const int rowTile = rt * BM, colTile = ct * BN;

    // per-thread staging coords: chunk q covers tile rows [q*16,q*16+16)
    const int q0 = w * 2, q1 = w * 2 + 1;
    const int e0 = q0 * 512 + lane * 8, e1 = q1 * 512 + lane * 8;
    const int rr0 = e0 >> 5, cc0 = e0 & 31;
    const int rr1 = e1 >> 5, cc1 = e1 & 31;
    const unsigned short* ga0 = xb + (size_t)(rowTile + rr0) * NDIM + cc0;
    const unsigned short* ga1 = xb + (size_t)(rowTile + rr1) * NDIM + cc1;
    const unsigned short* gb0 = xb + (size_t)(colTile + rr0) * NDIM + cc0;
    const unsigned short* gb1 = xb + (size_t)(colTile + rr1) * NDIM + cc1;

    f32x4 acc[4][4];
    const f32x4 zero = {0.f, 0.f, 0.f, 0.f};
#pragma unroll
    for (int i = 0; i < 4; ++i)
#pragma unroll
        for (int j = 0; j < 4; ++j) acc[i][j] = zero;

    // prologue: stage K-step 0 into buffer 0
    GLD_LDS16(ga0, &smem[0][0][q0 * 512]);
    GLD_LDS16(ga1, &smem[0][0][q1 * 512]);
    if (!diag) {
        GLD_LDS16(gb0, &smem[0][1][q0 * 512]);
        GLD_LDS16(gb1, &smem[0][1][q1 * 512]);
    }

    int cur = 0;
    for (int kt = 0; kt < NK; ++kt) {
        // issue next K-step's loads; they stay in flight across both barriers
        if (kt + 1 < NK) {
            const int k1 = (kt + 1) * BK;
            GLD_LDS16(ga0 + k1, &smem[cur ^ 1][0][q0 * 512]);
            GLD_LDS16(ga1 + k1, &smem[cur ^ 1][0][q1 * 512]);
            if (!diag) {
                GLD_LDS16(gb0 + k1, &smem[cur ^ 1][1][q0 * 512]);
                GLD_LDS16(gb1 + k1, &smem[cur ^ 1][1][q1 * 512]);
                asm volatile("s_waitcnt vmcnt(4)" ::: "memory");  // cur's 4 loads done
            } else {
                asm volatile("s_waitcnt vmcnt(2)" ::: "memory");  // cur's 2 loads done
            }
        } else {
            asm volatile("s_waitcnt vmcnt(0)" ::: "memory");
        }
        __builtin_amdgcn_s_barrier();            // all waves: cur buffer ready

        const unsigned short* AA = &smem[cur][0][0];
        const unsigned short* BB = diag ? AA : &smem[cur][1][0];
        bf16x8 af[4], bfr[4];
#pragma unroll
        for (int mi = 0; mi < 4; ++mi)
            af[mi] = *(const bf16x8*)&AA[(wr * 64 + mi * 16 + qq) * BK + g * 8];
#pragma unroll
        for (int ni = 0; ni < 4; ++ni)
            bfr[ni] = *(const bf16x8*)&BB[(wc * 64 + ni * 16 + qq) * BK + g * 8];
#pragma unroll
        for (int mi = 0; mi < 4; ++mi)
#pragma unroll
            for (int ni = 0; ni < 4; ++ni)
                acc[mi][ni] = __builtin_amdgcn_mfma_f32_16x16x32_bf16(af[mi], bfr[ni],
                                                                      acc[mi][ni], 0, 0, 0);
        asm volatile("s_waitcnt lgkmcnt(0)" ::: "memory");  // reads drained to regs
        __builtin_amdgcn_s_barrier();            // release cur for overwrite
        cur ^= 1;
    }

    // ---- epilogue ----
    // log2 domain: s2 = -dist * 10^T * log2(e)
    const float c2 = __builtin_amdgcn_exp2f(Tp[0] * 3.321928094887362f) * 1.4426950408889634f;
    float scol[4];
    int   ycol[4];
#pragma unroll
    for (int ni = 0; ni < 4; ++ni) {
        int C = colTile + wc * 64 + ni * 16 + qq;
        scol[ni] = sqn[C];
        ycol[ni] = y[C];
    }

    // phase 1: acc := s2 in place; label-match bits -> mm0/mm1
    unsigned mm0 = 0, mm1 = 0;
#pragma unroll
    for (int mi = 0; mi < 4; ++mi) {
        float srow4[4]; int yrow4[4];
#pragma unroll
        for (int r = 0; r < 4; ++r) {
            int R = rowTile + wr * 64 + mi * 16 + g * 4 + r;
            srow4[r] = sqn[R];
            yrow4[r] = y[R];
        }
#pragma unroll
        for (int r = 0; r < 4; ++r) {
            const int R = rowTile + wr * 64 + mi * 16 + g * 4 + r;
#pragma unroll
            for (int ni = 0; ni < 4; ++ni) {
                const int C = colTile + wc * 64 + ni * 16 + qq;
                float sq = fmaf(-2.f, acc[mi][ni][r], srow4[r] + scol[ni]);
                sq = fmaxf(sq, 0.f);
                float s2 = -__builtin_amdgcn_sqrtf(sq) * c2;
                if (R == C) s2 = NEG_INF;          // diagonal mask
                acc[mi][ni][r] = s2;
                unsigned bit = (yrow4[r] == ycol[ni]) ? 1u : 0u;
                int idx = ((mi & 1) * 4 + r) * 4 + ni;
                if (mi < 2) mm0 |= bit << idx; else mm1 |= bit << idx;
            }
        }
    }

    // phase 2: row-side partials (reduce over ni in-reg + 16 qq lanes)
#pragma unroll
    for (int mi = 0; mi < 4; ++mi) {
        unsigned mmw = (mi < 2) ? mm0 : mm1;
#pragma unroll
        for (int r = 0; r < 4; ++r) {
            float mx = acc[mi][0][r];
#pragma unroll
            for (int ni = 1; ni < 4; ++ni) mx = fmaxf(mx, acc[mi][ni][r]);
#pragma unroll
            for (int off = 1; off <= 8; off <<= 1) mx = fmaxf(mx, __shfl_xor(mx, off, 64));
            float ld = 0.f, ln = 0.f;
#pragma unroll
            for (int ni = 0; ni < 4; ++ni) {
                float e = __builtin_amdgcn_exp2f(acc[mi][ni][r] - mx);  // diag: exp2(-inf)=0
                ld += e;
                ln += ((mmw >> (((mi & 1) * 4 + r) * 4 + ni)) & 1) ? e : 0.f;
            }
#pragma unroll
            for (int off = 1; off <= 8; off <<= 1) {
                ld += __shfl_xor(ld, off, 64);
                ln += __shfl_xor(ln, off, 64);
            }
            if (qq == 0) {
                int lr = wr * 64 + mi * 16 + g * 4 + r;
                redR[(lr * 2 + wc) * 4 + 0] = mx;
                redR[(lr * 2 + wc) * 4 + 1] = ld;
                redR[(lr * 2 + wc) * 4 + 2] = ln;
            }
        }
    }

    // phase 3: col-side partials (reduce over mi,r in-reg + g lanes), off-diag only
    if (!diag) {
#pragma unroll
        for (int ni = 0; ni < 4; ++ni) {
            float mx = NEG_INF;
#pragma unroll
            for (int mi = 0; mi < 4; ++mi)
#pragma unroll
                for (int r = 0; r < 4; ++r) mx = fmaxf(mx, acc[mi][ni][r]);
            mx = fmaxf(mx, __shfl_xor(mx, 16, 64));
            mx = fmaxf(mx, __shfl_xor(mx, 32, 64));
            float ld = 0.f, ln = 0.f;
#pragma unroll
            for (int mi = 0; mi < 4; ++mi) {
                unsigned mmw = (mi < 2) ? mm0 : mm1;
#pragma unroll
                for (int r = 0; r < 4; ++r) {
                    float e = __builtin_amdgcn_exp2f(acc[mi][ni][r] - mx);
                    ld += e;
                    ln += ((mmw >> (((mi & 1) * 4 + r) * 4 + ni)) & 1) ? e : 0.f;
                }
            }
            ld += __shfl_xor(ld, 16, 64); ld += __shfl_xor(ld, 32, 64);
            ln += __shfl_xor(ln, 16, 64); ln += __shfl_xor(ln, 32, 64);
            if (g == 0) {
                int lc = wc * 64 + ni * 16 + qq;
                redC[(lc * 2 + wr) * 4 + 0] = mx;
                redC[(lc * 2 + wr) * 4 + 1] = ld;
                redC[(lc * 2 + wr) * 4 + 2] = ln;
            }
        }
    }
    __syncthreads();

    if (tid < BM) {
        {
            float m0 = redR[(tid * 2 + 0) * 4 + 0], l0 = redR[(tid * 2 + 0) * 4 + 1],
                  n0 = redR[(tid * 2 + 0) * 4 + 2];
            float m1 = redR[(tid * 2 + 1) * 4 + 0], l1 = redR[(tid * 2 + 1) * 4 + 1],
                  n1 = redR[(tid * 2 + 1) * 4 + 2];
            float M = fmaxf(m0, m1);
            float e0 = __builtin_amdgcn_exp2f(m0 - M), e1 = __builtin_amdgcn_exp2f(m1 - M);
            float4 o; o.x = M; o.y = l0 * e0 + l1 * e1; o.z = n0 * e0 + n1 * e1; o.w = 0.f;
            part[(size_t)ct * NROW + rowTile + tid] = o;
        }
        if (!diag) {
            float m0 = redC[(tid * 2 + 0) * 4 + 0], l0 = redC[(tid * 2 + 0) * 4 + 1],
                  n0 = redC[(tid * 2 + 0) * 4 + 2];
            float m1 = redC[(tid * 2 + 1) * 4 + 0], l1 = redC[(tid * 2 + 1) * 4 + 1],
                  n1 = redC[(tid * 2 + 1) * 4 + 2];
            float M = fmaxf(m0, m1);
            float e0 = __builtin_amdgcn_exp2f(m0 - M), e1 = __builtin_amdgcn_exp2f(m1 - M);
            float4 o; o.x = M; o.y = l0 * e0 + l1 * e1; o.z = n0 * e0 + n1 * e1; o.w = 0.f;
            part[(size_t)rt * NROW + colTile + tid] = o;
        }
    }
}

// ---------------- combine chunks per row ----------------
__global__ __launch_bounds__(256) void k_rows(const float4* __restrict__ part,
                                              float* __restrict__ rowv) {
    int r = blockIdx.x * 256 + threadIdx.x;
    float M = NEG_INF, L = 0.f, Ln = 0.f;
    for (int ctt = 0; ctt < NT; ++ctt) {
        float4 p = part[(size_t)ctt * NROW + r];
        float m = p.x;                             // always finite
        if (m > M) {
            float sc = __builtin_amdgcn_exp2f(M - m);  // first iter: exp2(-inf)=0
            L *= sc; Ln *= sc; M = m;
        }
        float s2 = __builtin_amdgcn_exp2f(m - M);
        L  += p.y * s2;
        Ln += p.z * s2;
    }
    float v = (Ln > 0.f) ? (__builtin_amdgcn_logf(Ln) - __builtin_amdgcn_logf(L))
                               * 0.69314718055994530942f
                         : 0.f;
    rowv[r] = v;
}

__global__ __launch_bounds__(256) void k_final(const float* __restrict__ rowv,
                                               float* __restrict__ out) {
    float s = 0.f;
    for (int i = threadIdx.x; i < NROW; i += 256) s += rowv[i];
#pragma unroll
    for (int off = 32; off >= 1; off >>= 1) s += __shfl_xor(s, off, 64);
    __shared__ float sa[4];
    int w = threadIdx.x >> 6, lane = threadIdx.x & 63;
    if (lane == 0) sa[w] = s;
    __syncthreads();
    if (threadIdx.x == 0) out[0] = -((sa[0] + sa[1] + sa[2] + sa[3]) / (float)NROW);
}

extern "C" void kernel_launch(void* const* d_in, const int* in_sizes, int n_in,
                              void* d_out, int out_size, void* d_ws, size_t ws_size,
                              hipStream_t stream) {
    (void)in_sizes; (void)n_in; (void)out_size; (void)ws_size;
    const float* x  = (const float*)d_in[0];
    const int*   y  = (const int*)d_in[1];
    const float* Tp = (const float*)d_in[2];
    float* out = (float*)d_out;

    char* ws = (char*)d_ws;
    double*         part2 = (double*)(ws + WS_PART);
    float*          scal  = (float*)(ws + WS_SCAL);
    unsigned short* xb    = (unsigned short*)(ws + WS_XB);
    float*          sqn   = (float*)(ws + WS_SQN);
    float4*         p4    = (float4*)(ws + WS_P4);
    float*          rowv  = (float*)(ws + WS_ROWV);

    k_stats <<<256, 256, 0, stream>>>(x, part2);
    k_stats2<<<1,   256, 0, stream>>>(part2, scal);
    k_norm  <<<NROW / 4, 256, 0, stream>>>(x, scal, xb, sqn);
    k_main  <<<NBLK, 256, 0, stream>>>(xb, sqn, y, Tp, p4);
    k_rows  <<<NROW / 256, 256, 0, stream>>>(p4, rowv);
    k_final <<<1, 256, 0, stream>>>(rowv, out);
}